// Round 7
// baseline (201.299 us; speedup 1.0000x reference)
//
#include <hip/hip_runtime.h>
#include <math.h>

#define Bn 4
#define Cn 256
#define Nn 1024
#define Hn 8
#define Dn 32
#define BHND (Bn * Hn * Nn * Dn)   // 1048576
#define BHN  (Bn * Hn * Nn)        // 32768

typedef short bf16x8 __attribute__((ext_vector_type(8)));
typedef float f32x4 __attribute__((ext_vector_type(4)));

__device__ inline unsigned f2bf_rn_bits(float x) {
  union { float f; unsigned u; } v; v.f = x;
  return (v.u + 0x7FFFu + ((v.u >> 16) & 1u)) >> 16;
}
__device__ inline float bfbits2f(unsigned b) {
  union { unsigned u; float f; } v; v.u = b << 16; return v.f;
}
__device__ inline void split_bf(float x, unsigned& hi, unsigned& lo) {
  hi = f2bf_rn_bits(x);
  lo = f2bf_rn_bits(x - bfbits2f(hi));
}
// truncation split (cheaper; lo absorbs hi error, ~2^-16 rel)
__device__ inline unsigned split_bf_trunc_pack(float x) {
  union { float f; unsigned u; } v; v.f = x;
  unsigned hi = v.u >> 16;
  union { unsigned u; float f; } hv; hv.u = hi << 16;
  union { float f; unsigned u; } r; r.f = x - hv.f;
  return hi | (r.u & 0xffff0000u);
}
__device__ inline void split4(const float4& a, float sc, short4& hs, short4& ls) {
  unsigned hb, lb;
  split_bf(a.x * sc, hb, lb); hs.x = (short)hb; ls.x = (short)lb;
  split_bf(a.y * sc, hb, lb); hs.y = (short)hb; ls.y = (short)lb;
  split_bf(a.z * sc, hb, lb); hs.z = (short)hb; ls.z = (short)lb;
  split_bf(a.w * sc, hb, lb); hs.w = (short)hb; ls.w = (short)lb;
}
__device__ inline void unpack_u32x8(const uint4& a, const uint4& b, bf16x8& hi, bf16x8& lo) {
  int4 h4, l4;
  h4.x = (int)((a.x & 0xffffu) | (a.y << 16));  l4.x = (int)((a.x >> 16) | (a.y & 0xffff0000u));
  h4.y = (int)((a.z & 0xffffu) | (a.w << 16));  l4.y = (int)((a.z >> 16) | (a.w & 0xffff0000u));
  h4.z = (int)((b.x & 0xffffu) | (b.y << 16));  l4.z = (int)((b.x >> 16) | (b.y & 0xffff0000u));
  h4.w = (int)((b.z & 0xffffu) | (b.w << 16));  l4.w = (int)((b.z >> 16) | (b.w & 0xffff0000u));
  hi = *(bf16x8*)&h4; lo = *(bf16x8*)&l4;
}

// ---------------- K1a: partial sums of da_prior over n-chunks ----------------
__global__ __launch_bounds__(256) void k_prior_part(const float* __restrict__ dap,
                                                    float* __restrict__ pp) {
  int bi = blockIdx.x;
  int b = bi >> 5, ch = bi & 31;
  int c = threadIdx.x;
  float s = 0.f;
  int n0 = ch * 32;
  for (int n = n0; n < n0 + 32; ++n) s += dap[(size_t)(b * Nn + n) * Cn + c];
  pp[(size_t)(b * 32 + ch) * Cn + c] = s;
}

// ---------------- K1b: reduce partials -> prior_sum[B,C] ----------------
__global__ __launch_bounds__(256) void k_prior_red(const float* __restrict__ pp,
                                                   float* __restrict__ prior) {
  int i = blockIdx.x * 256 + threadIdx.x;
  int b = i >> 8, c = i & 255;
  float s = 0.f;
  for (int ch = 0; ch < 32; ++ch) s += pp[(size_t)(b * 32 + ch) * Cn + c];
  prior[i] = s;
}

// ---------------- K2: prep (diag*x*prior + x) + LayerNorm, direct ne read, fp32 out ----
// XCD-swizzled block->n mapping for L2 locality of the strided ne reads.
__global__ __launch_bounds__(256) void k_prep_ln(const float* __restrict__ ne,
                                                 const float* __restrict__ eg,
                                                 const float* __restrict__ prior,
                                                 const float* __restrict__ gamma,
                                                 const float* __restrict__ beta,
                                                 float* __restrict__ ln) {
  int blk = blockIdx.x;              // Bn*Nn
  int xcd = blk & 7, idx = blk >> 3;
  int b = idx >> 7;
  int n = xcd * 128 + (idx & 127);
  int c = threadIdx.x;
  float x = ne[(size_t)(b * Cn + c) * Nn + n];
  float dg = eg[(size_t)(b * Nn + n) * Nn + n];
  float x2 = x * (1.f + dg * prior[b * Cn + c]);
  float s = x2, qq = x2 * x2;
#pragma unroll
  for (int off = 32; off >= 1; off >>= 1) {
    s += __shfl_xor(s, off);
    qq += __shfl_xor(qq, off);
  }
  __shared__ float ss[4], sq[4];
  if ((c & 63) == 0) { ss[c >> 6] = s; sq[c >> 6] = qq; }
  __syncthreads();
  s = ss[0] + ss[1] + ss[2] + ss[3];
  qq = sq[0] + sq[1] + sq[2] + sq[3];
  float mu = s * (1.f / 256.f);
  float var = qq * (1.f / 256.f) - mu * mu;
  float r = rsqrtf(var + 1e-5f);
  ln[(size_t)(b * Nn + n) * Cn + c] = (x2 - mu) * r * gamma[c] + beta[c];
}

// ---------------- K3: QKV GEMM (fp32, round-5 proven); epilogue emits Q/K planes + V^T planes ----
__global__ __launch_bounds__(256) void k_qkv_gemm(const float* __restrict__ ln,
                                                  const float* __restrict__ wqkv,
                                                  short* __restrict__ q_hi,
                                                  short* __restrict__ q_lo,
                                                  short* __restrict__ k_hi,
                                                  short* __restrict__ k_lo,
                                                  short* __restrict__ vt_hi,
                                                  short* __restrict__ vt_lo) {
  __shared__ __align__(16) float at[16][68];
  __shared__ __align__(16) float bt[16][68];
  __shared__ float ct[64][65];
  int m0 = blockIdx.x * 64;
  int j0 = blockIdx.y * 64;
  int t = threadIdx.x;
  int tx = t & 15, ty = t >> 4;
  float4 acc[4] = {};
  for (int k0 = 0; k0 < 256; k0 += 16) {
    {
      int row = t >> 2, k4 = (t & 3) << 2;
      float4 a = *(const float4*)&ln[(size_t)(m0 + row) * 256 + k0 + k4];
      at[k4 + 0][row] = a.x; at[k4 + 1][row] = a.y;
      at[k4 + 2][row] = a.z; at[k4 + 3][row] = a.w;
      int rb = t >> 4, jb = (t & 15) << 2;
      *(float4*)&bt[rb][jb] = *(const float4*)&wqkv[(size_t)(k0 + rb) * 768 + j0 + jb];
    }
    __syncthreads();
#pragma unroll
    for (int kk = 0; kk < 16; ++kk) {
      float4 a4 = *(float4*)&at[kk][ty << 2];
      float4 b4 = *(float4*)&bt[kk][tx << 2];
      acc[0].x += a4.x * b4.x; acc[0].y += a4.x * b4.y; acc[0].z += a4.x * b4.z; acc[0].w += a4.x * b4.w;
      acc[1].x += a4.y * b4.x; acc[1].y += a4.y * b4.y; acc[1].z += a4.y * b4.z; acc[1].w += a4.y * b4.w;
      acc[2].x += a4.z * b4.x; acc[2].y += a4.z * b4.y; acc[2].z += a4.z * b4.z; acc[2].w += a4.z * b4.w;
      acc[3].x += a4.w * b4.x; acc[3].y += a4.w * b4.y; acc[3].z += a4.w * b4.z; acc[3].w += a4.w * b4.w;
    }
    __syncthreads();
  }
  int b = m0 >> 10, n0 = m0 & 1023;
  int three = (j0 + (tx << 2)) >> 8;   // block-uniform
  const float scale = 0.17677669529663687f;  // 1/sqrt(32), folded into K planes
  if (three == 2) {
    // V block: LDS transpose -> write V^T bf16 planes [B,H,D,N]
#pragma unroll
    for (int i = 0; i < 4; ++i) {
      ct[(ty << 2) + i][(tx << 2) + 0] = acc[i].x;
      ct[(ty << 2) + i][(tx << 2) + 1] = acc[i].y;
      ct[(ty << 2) + i][(tx << 2) + 2] = acc[i].z;
      ct[(ty << 2) + i][(tx << 2) + 3] = acc[i].w;
    }
    __syncthreads();
    int jl = t >> 2;            // local j 0..63
    int n4 = (t & 3) * 16;      // 16 n-values per thread
    int rem = (j0 & 255) + jl;
    int h = rem >> 5, d = rem & 31;
    short hs[16], ls[16];
#pragma unroll
    for (int u = 0; u < 16; ++u) {
      unsigned hb, lb;
      split_bf(ct[n4 + u][jl], hb, lb);
      hs[u] = (short)hb; ls[u] = (short)lb;
    }
    size_t ob = ((size_t)(b * Hn + h) * Dn + d) * Nn + n0 + n4;
    *(uint4*)&vt_hi[ob] = *(uint4*)&hs[0];
    *(uint4*)&vt_hi[ob + 8] = *(uint4*)&hs[8];
    *(uint4*)&vt_lo[ob] = *(uint4*)&ls[0];
    *(uint4*)&vt_lo[ob + 8] = *(uint4*)&ls[8];
  } else {
    int j = j0 + (tx << 2);
    int rem = j & 255, h = rem >> 5, dd = rem & 31;
    short* dst_hi = (three == 0) ? q_hi : k_hi;
    short* dst_lo = (three == 0) ? q_lo : k_lo;
    float sc = (three == 0) ? 1.0f : scale;
#pragma unroll
    for (int i = 0; i < 4; ++i) {
      int m = m0 + (ty << 2) + i;
      int bb = m >> 10, n = m & 1023;
      size_t base = (size_t)((bb * Hn + h) * Nn + n) * Dn + dd;
      short4 hs, ls; split4(acc[i], sc, hs, ls);
      *(short4*)&dst_hi[base] = hs; *(short4*)&dst_lo[base] = ls;
    }
  }
}

// ---------------- K4a: MFMA attention core (m-split x2), unnormalized partials ----------
__global__ __launch_bounds__(256, 4) void k_attn_core(
    const short* __restrict__ q_hi, const short* __restrict__ q_lo,
    const short* __restrict__ k_hi, const short* __restrict__ k_lo,
    const short* __restrict__ vt_hi, const short* __restrict__ vt_lo,
    const float* __restrict__ eg,
    const float* __restrict__ w_expand, const float* __restrict__ b_expand,
    float* __restrict__ o_part, float* __restrict__ l_part) {
  __shared__ short kh[64 * 40];
  __shared__ short kl[64 * 40];
  __shared__ short vth[32 * 72];
  __shared__ short vtl[32 * 72];
  __shared__ unsigned pbuf[4][16 * 68];

  int blk = blockIdx.x;
  int mh = blk & 1;
  int nt = (blk >> 1) & 15;
  int h = (blk >> 5) & 7;
  int b = blk >> 8;
  int n0 = nt * 64;
  int t = threadIdx.x, wid = t >> 6, l = t & 63;
  int lr = l & 15, lq = l >> 4;

  const float we = w_expand[h], be = b_expand[h];
  size_t bhb = (size_t)(b * Hn + h) * Nn * Dn;
  const short* khg = k_hi + bhb;
  const short* klg = k_lo + bhb;
  const short* vhg = vt_hi + bhb;
  const short* vlg = vt_lo + bhb;

  bf16x8 qhi, qlo;
  {
    size_t qoff = bhb + (size_t)(n0 + wid * 16 + lr) * Dn + lq * 8;
    qhi = *(const bf16x8*)&q_hi[qoff];
    qlo = *(const bf16x8*)&q_lo[qoff];
  }

  f32x4 O0 = {0.f, 0.f, 0.f, 0.f}, O1 = {0.f, 0.f, 0.f, 0.f};
  float rowsum[4] = {0.f, 0.f, 0.f, 0.f};
  int nrow = n0 + wid * 16 + lq * 4;

  for (int ms = 0; ms < 8; ++ms) {
    int m0 = mh * 512 + ms * 64;
    float eb[4][4];
#pragma unroll
    for (int reg = 0; reg < 4; ++reg) {
      const float* ep = &eg[(size_t)(b * Nn + nrow + reg) * Nn + m0 + lr];
#pragma unroll
      for (int msub = 0; msub < 4; ++msub) eb[msub][reg] = ep[msub * 16];
    }
    __syncthreads();
    {
      int row = t >> 2, c = (t & 3) * 8;
      *(uint4*)&kh[row * 40 + c] = *(const uint4*)&khg[(size_t)(m0 + row) * Dn + c];
      *(uint4*)&kl[row * 40 + c] = *(const uint4*)&klg[(size_t)(m0 + row) * Dn + c];
      int d = t >> 3, cm = (t & 7) * 8;
      *(uint4*)&vth[d * 72 + cm] = *(const uint4*)&vhg[(size_t)d * Nn + m0 + cm];
      *(uint4*)&vtl[d * 72 + cm] = *(const uint4*)&vlg[(size_t)d * Nn + m0 + cm];
    }
    __syncthreads();

#pragma unroll
    for (int msub = 0; msub < 4; ++msub) {
      int mrow = msub * 16 + lr;
      bf16x8 bh8 = *(bf16x8*)&kh[mrow * 40 + lq * 8];
      bf16x8 bl8 = *(bf16x8*)&kl[mrow * 40 + lq * 8];
      f32x4 sacc = {0.f, 0.f, 0.f, 0.f};
      sacc = __builtin_amdgcn_mfma_f32_16x16x32_bf16(qlo, bh8, sacc, 0, 0, 0);
      sacc = __builtin_amdgcn_mfma_f32_16x16x32_bf16(qhi, bl8, sacc, 0, 0, 0);
      sacc = __builtin_amdgcn_mfma_f32_16x16x32_bf16(qhi, bh8, sacc, 0, 0, 0);
#pragma unroll
      for (int reg = 0; reg < 4; ++reg) {
        float s = sacc[reg] + eb[msub][reg] * we + be;
        float e = __expf(s);
        rowsum[reg] += e;
        pbuf[wid][(lq * 4 + reg) * 68 + msub * 16 + lr] = split_bf_trunc_pack(e);
      }
    }

#pragma unroll
    for (int mw = 0; mw < 2; ++mw) {
      uint4 pa = *(uint4*)&pbuf[wid][lr * 68 + mw * 32 + lq * 8];
      uint4 pb = *(uint4*)&pbuf[wid][lr * 68 + mw * 32 + lq * 8 + 4];
      bf16x8 ahi, alo;
      unpack_u32x8(pa, pb, ahi, alo);
      {
        bf16x8 vh8 = *(bf16x8*)&vth[lr * 72 + mw * 32 + lq * 8];
        bf16x8 vl8 = *(bf16x8*)&vtl[lr * 72 + mw * 32 + lq * 8];
        O0 = __builtin_amdgcn_mfma_f32_16x16x32_bf16(alo, vh8, O0, 0, 0, 0);
        O0 = __builtin_amdgcn_mfma_f32_16x16x32_bf16(ahi, vl8, O0, 0, 0, 0);
        O0 = __builtin_amdgcn_mfma_f32_16x16x32_bf16(ahi, vh8, O0, 0, 0, 0);
      }
      {
        bf16x8 vh8 = *(bf16x8*)&vth[(16 + lr) * 72 + mw * 32 + lq * 8];
        bf16x8 vl8 = *(bf16x8*)&vtl[(16 + lr) * 72 + mw * 32 + lq * 8];
        O1 = __builtin_amdgcn_mfma_f32_16x16x32_bf16(alo, vh8, O1, 0, 0, 0);
        O1 = __builtin_amdgcn_mfma_f32_16x16x32_bf16(ahi, vl8, O1, 0, 0, 0);
        O1 = __builtin_amdgcn_mfma_f32_16x16x32_bf16(ahi, vh8, O1, 0, 0, 0);
      }
    }
  }

#pragma unroll
  for (int reg = 0; reg < 4; ++reg) {
#pragma unroll
    for (int off = 1; off < 16; off <<= 1)
      rowsum[reg] += __shfl_xor(rowsum[reg], off);
  }
  size_t pbase = (size_t)mh * BHND + bhb;
#pragma unroll
  for (int reg = 0; reg < 4; ++reg) {
    int n = nrow + reg;
    o_part[pbase + (size_t)n * Dn + lr] = O0[reg];
    o_part[pbase + (size_t)n * Dn + 16 + lr] = O1[reg];
    if (lr == 0)
      l_part[(size_t)mh * BHN + (size_t)(b * Hn + h) * Nn + n] = rowsum[reg];
  }
}

// ---------------- K4b: edge output: recompute S, edge = sum_h wr*(p+s) + br ------
__global__ __launch_bounds__(256, 4) void k_edge_mfma(
    const short* __restrict__ q_hi, const short* __restrict__ q_lo,
    const short* __restrict__ k_hi, const short* __restrict__ k_lo,
    const float* __restrict__ eg, const float* __restrict__ l_part,
    const float* __restrict__ w_expand, const float* __restrict__ b_expand,
    const float* __restrict__ w_reduce, const float* __restrict__ b_reduce,
    float* __restrict__ edge_out) {
  __shared__ short kh[64 * 40];
  __shared__ short kl[64 * 40];
  int blk = blockIdx.x;
  int mt = blk & 15;
  int nt = (blk >> 4) & 15;
  int b = blk >> 8;
  int n0 = nt * 64, m0 = mt * 64;
  int t = threadIdx.x, wid = t >> 6, l = t & 63;
  int lr = l & 15, lq = l >> 4;
  const float br = b_reduce[0];
  int nrow = n0 + wid * 16 + lq * 4;

  float eacc[4][4], ebias[4][4];
#pragma unroll
  for (int reg = 0; reg < 4; ++reg) {
    const float* ep = &eg[(size_t)(b * Nn + nrow + reg) * Nn + m0 + lr];
#pragma unroll
    for (int msub = 0; msub < 4; ++msub) {
      ebias[msub][reg] = ep[msub * 16];
      eacc[msub][reg] = br;
    }
  }

  for (int h = 0; h < Hn; ++h) {
    size_t bhb = (size_t)(b * Hn + h) * Nn * Dn;
    float we = w_expand[h], be = b_expand[h], wr = w_reduce[h];
    bf16x8 qhi, qlo;
    {
      size_t qoff = bhb + (size_t)(n0 + wid * 16 + lr) * Dn + lq * 8;
      qhi = *(const bf16x8*)&q_hi[qoff];
      qlo = *(const bf16x8*)&q_lo[qoff];
    }
    float invl[4];
#pragma unroll
    for (int reg = 0; reg < 4; ++reg) {
      size_t sidx = (size_t)(b * Hn + h) * Nn + nrow + reg;
      invl[reg] = 1.0f / (l_part[sidx] + l_part[BHN + sidx]);
    }

    __syncthreads();
    {
      int row = t >> 2, c = (t & 3) * 8;
      *(uint4*)&kh[row * 40 + c] = *(const uint4*)&k_hi[bhb + (size_t)(m0 + row) * Dn + c];
      *(uint4*)&kl[row * 40 + c] = *(const uint4*)&k_lo[bhb + (size_t)(m0 + row) * Dn + c];
    }
    __syncthreads();
#pragma unroll
    for (int msub = 0; msub < 4; ++msub) {
      int mrow = msub * 16 + lr;
      bf16x8 bh8 = *(bf16x8*)&kh[mrow * 40 + lq * 8];
      bf16x8 bl8 = *(bf16x8*)&kl[mrow * 40 + lq * 8];
      f32x4 sacc = {0.f, 0.f, 0.f, 0.f};
      sacc = __builtin_amdgcn_mfma_f32_16x16x32_bf16(qlo, bh8, sacc, 0, 0, 0);
      sacc = __builtin_amdgcn_mfma_f32_16x16x32_bf16(qhi, bl8, sacc, 0, 0, 0);
      sacc = __builtin_amdgcn_mfma_f32_16x16x32_bf16(qhi, bh8, sacc, 0, 0, 0);
#pragma unroll
      for (int reg = 0; reg < 4; ++reg) {
        float s = sacc[reg] + ebias[msub][reg] * we + be;
        float p = __expf(s) * invl[reg];
        eacc[msub][reg] += wr * (p + s);
      }
    }
  }
#pragma unroll
  for (int msub = 0; msub < 4; ++msub)
#pragma unroll
    for (int reg = 0; reg < 4; ++reg)
      edge_out[(size_t)(b * Nn + nrow + reg) * Nn + m0 + msub * 16 + lr] = eacc[msub][reg];
}

// ---------------- K5: edge softmax + wsum ----------------
__global__ __launch_bounds__(256) void k_edge_soft(const float* __restrict__ edge,
                                                   float* __restrict__ wsum) {
  int bn = blockIdx.x;
  int t = threadIdx.x;
  const float* row = edge + (size_t)bn * Nn;
  float4 e = *(const float4*)&row[t * 4];
  float mx = fmaxf(fmaxf(e.x, e.y), fmaxf(e.z, e.w));
#pragma unroll
  for (int off = 32; off >= 1; off >>= 1) mx = fmaxf(mx, __shfl_xor(mx, off));
  __shared__ float sm[4], sl[4], sw[4];
  if ((t & 63) == 0) sm[t >> 6] = mx;
  __syncthreads();
  mx = fmaxf(fmaxf(sm[0], sm[1]), fmaxf(sm[2], sm[3]));
  float p0 = __expf(e.x - mx), p1 = __expf(e.y - mx), p2 = __expf(e.z - mx), p3 = __expf(e.w - mx);
  float ls = p0 + p1 + p2 + p3;
  float ws = p0 * e.x + p1 * e.y + p2 * e.z + p3 * e.w;
#pragma unroll
  for (int off = 32; off >= 1; off >>= 1) { ls += __shfl_xor(ls, off); ws += __shfl_xor(ws, off); }
  if ((t & 63) == 0) { sl[t >> 6] = ls; sw[t >> 6] = ws; }
  __syncthreads();
  if (t == 0) {
    float L = sl[0] + sl[1] + sl[2] + sl[3];
    float Wv = sw[0] + sw[1] + sw[2] + sw[3];
    wsum[bn] = Wv / L;
  }
}

// ---------------- K6: ((o0+o1)*invl + wsum*w_fc + b_fc) @ w_proj + b_proj ----------
__global__ __launch_bounds__(256) void k_proj_gemm(const float* __restrict__ o_part,
                                                   const float* __restrict__ l_part,
                                                   const float* __restrict__ wsum,
                                                   const float* __restrict__ wfc,
                                                   const float* __restrict__ bfc,
                                                   const float* __restrict__ wproj,
                                                   const float* __restrict__ bproj,
                                                   float* __restrict__ out) {
  __shared__ __align__(16) float at[16][68];
  __shared__ __align__(16) float bt[16][68];
  __shared__ float ct[64][65];
  int m0 = blockIdx.x * 64;
  int j0 = blockIdx.y * 64;
  int t = threadIdx.x;
  int tx = t & 15, ty = t >> 4;
  float4 acc[4] = {};
  for (int k0 = 0; k0 < 256; k0 += 16) {
    {
      int row = t >> 2, k4 = (t & 3) << 2;
      int m = m0 + row;
      int bb = m >> 10, n = m & 1023;
      int c = k0 + k4;
      int h = c >> 5, dd = c & 31;
      float wsm = wsum[m];
      size_t ob = ((size_t)(bb * Hn + h) * Nn + n) * Dn + dd;
      float4 oa = *(const float4*)&o_part[ob];
      float4 oc = *(const float4*)&o_part[BHND + ob];
      size_t sidx = (size_t)(bb * Hn + h) * Nn + n;
      float inv = 1.0f / (l_part[sidx] + l_part[BHN + sidx]);
      float4 a;
      a.x = (oa.x + oc.x) * inv + wsm * wfc[c + 0] + bfc[c + 0];
      a.y = (oa.y + oc.y) * inv + wsm * wfc[c + 1] + bfc[c + 1];
      a.z = (oa.z + oc.z) * inv + wsm * wfc[c + 2] + bfc[c + 2];
      a.w = (oa.w + oc.w) * inv + wsm * wfc[c + 3] + bfc[c + 3];
      at[k4 + 0][row] = a.x; at[k4 + 1][row] = a.y;
      at[k4 + 2][row] = a.z; at[k4 + 3][row] = a.w;
      int rb = t >> 4, jb = (t & 15) << 2;
      *(float4*)&bt[rb][jb] = *(const float4*)&wproj[(size_t)(k0 + rb) * 256 + j0 + jb];
    }
    __syncthreads();
#pragma unroll
    for (int kk = 0; kk < 16; ++kk) {
      float4 a4 = *(float4*)&at[kk][ty << 2];
      float4 b4 = *(float4*)&bt[kk][tx << 2];
      acc[0].x += a4.x * b4.x; acc[0].y += a4.x * b4.y; acc[0].z += a4.x * b4.z; acc[0].w += a4.x * b4.w;
      acc[1].x += a4.y * b4.x; acc[1].y += a4.y * b4.y; acc[1].z += a4.y * b4.z; acc[1].w += a4.y * b4.w;
      acc[2].x += a4.z * b4.x; acc[2].y += a4.z * b4.y; acc[2].z += a4.z * b4.z; acc[2].w += a4.z * b4.w;
      acc[3].x += a4.w * b4.x; acc[3].y += a4.w * b4.y; acc[3].z += a4.w * b4.z; acc[3].w += a4.w * b4.w;
    }
    __syncthreads();
  }
#pragma unroll
  for (int i = 0; i < 4; ++i) {
    ct[(ty << 2) + i][(tx << 2) + 0] = acc[i].x + bproj[j0 + (tx << 2) + 0];
    ct[(ty << 2) + i][(tx << 2) + 1] = acc[i].y + bproj[j0 + (tx << 2) + 1];
    ct[(ty << 2) + i][(tx << 2) + 2] = acc[i].z + bproj[j0 + (tx << 2) + 2];
    ct[(ty << 2) + i][(tx << 2) + 3] = acc[i].w + bproj[j0 + (tx << 2) + 3];
  }
  __syncthreads();
  int b = m0 >> 10, n0 = m0 & 1023;
  int n4 = t & 15, c0i = t >> 4;
#pragma unroll
  for (int u = 0; u < 4; ++u) {
    int ci = c0i + u * 16;
    float4 val = { ct[(n4 << 2) + 0][ci], ct[(n4 << 2) + 1][ci],
                   ct[(n4 << 2) + 2][ci], ct[(n4 << 2) + 3][ci] };
    *(float4*)&out[(size_t)(b * Cn + j0 + ci) * Nn + n0 + (n4 << 2)] = val;
  }
}

// ---------------- launch ----------------
extern "C" void kernel_launch(void* const* d_in, const int* in_sizes, int n_in,
                              void* d_out, int out_size, void* d_ws, size_t ws_size,
                              hipStream_t stream) {
  (void)in_sizes; (void)n_in; (void)out_size; (void)ws_size;
  const float* node_embeds = (const float*)d_in[0];
  const float* edge_embeds = (const float*)d_in[1];
  const float* da_prior    = (const float*)d_in[2];
  const float* gamma       = (const float*)d_in[3];
  const float* beta        = (const float*)d_in[4];
  const float* w_qkv       = (const float*)d_in[5];
  const float* w_proj      = (const float*)d_in[6];
  const float* b_proj      = (const float*)d_in[7];
  const float* w_expand    = (const float*)d_in[8];
  const float* b_expand    = (const float*)d_in[9];
  const float* w_reduce    = (const float*)d_in[10];
  const float* b_reduce    = (const float*)d_in[11];
  const float* w_fc        = (const float*)d_in[12];
  const float* b_fc        = (const float*)d_in[13];
  float* out_node = (float*)d_out;
  float* out_edge = out_node + (size_t)Bn * Cn * Nn;

  const size_t M = 1048576;  // B*N*C elements
  float* W = (float*)d_ws;
  // [0, 2M): o_part [2][B,H,N,D]; ln (fp32) at [M,2M) is dead before attn_core writes.
  // [2M,3M): V^T bf16 planes; [3M,5M): q/k bf16 hi/lo planes.
  float* o_part = W;
  float* ws_ln  = W + M;
  short* vt_hi  = (short*)(W + 2 * M);
  short* vt_lo  = vt_hi + M;
  short* q_hi   = (short*)(W + 3 * M);
  short* q_lo   = q_hi + M;
  short* k_hi   = q_hi + 2 * M;
  short* k_lo   = q_hi + 3 * M;
  float* ws_pp    = W + 5 * M;
  float* ws_prior = ws_pp + Bn * 32 * Cn;
  float* ws_wsum  = ws_prior + Bn * Cn;
  float* l_part   = ws_wsum + Bn * Nn;          // [2][B,H,N]

  k_prior_part<<<dim3(Bn * 32), dim3(256), 0, stream>>>(da_prior, ws_pp);
  k_prior_red<<<dim3(Bn), dim3(256), 0, stream>>>(ws_pp, ws_prior);
  k_prep_ln<<<dim3(Bn * Nn), dim3(256), 0, stream>>>(node_embeds, edge_embeds,
                                                     ws_prior, gamma, beta, ws_ln);
  k_qkv_gemm<<<dim3(64, 12), dim3(256), 0, stream>>>(ws_ln, w_qkv, q_hi, q_lo,
                                                     k_hi, k_lo, vt_hi, vt_lo);
  k_attn_core<<<dim3(Bn * Hn * 16 * 2), dim3(256), 0, stream>>>(
      q_hi, q_lo, k_hi, k_lo, vt_hi, vt_lo, edge_embeds, w_expand, b_expand,
      o_part, l_part);
  k_edge_mfma<<<dim3(Bn * 16 * 16), dim3(256), 0, stream>>>(
      q_hi, q_lo, k_hi, k_lo, edge_embeds, l_part, w_expand, b_expand,
      w_reduce, b_reduce, out_edge);
  k_edge_soft<<<dim3(Bn * Nn), dim3(256), 0, stream>>>(out_edge, ws_wsum);
  k_proj_gemm<<<dim3(64, 4), dim3(256), 0, stream>>>(o_part, l_part, ws_wsum,
                                                     w_fc, b_fc, w_proj, b_proj,
                                                     out_node);
}